// Round 6
// baseline (11373.333 us; speedup 1.0000x reference)
//
#include <hip/hip_runtime.h>

#define VOCAB   30
#define EMBED   256
#define KVS     128
#define BATCH   128
#define T_ENC   1024
#define MAX_LEN 250
#define NTH     1024
#define HALF_T  512

typedef unsigned int uint32;
typedef unsigned short ushort16;

__device__ __forceinline__ float dot4(float4 a, float4 b) {
  return a.x * b.x + a.y * b.y + a.z * b.z + a.w * b.w;
}
__device__ __forceinline__ float bf_lo(uint32 u) { return __uint_as_float(u << 16); }
__device__ __forceinline__ float bf_hi(uint32 u) { return __uint_as_float(u & 0xffff0000u); }
__device__ __forceinline__ ushort16 f2bf(float f) {
  uint32 u = __float_as_uint(f);
  return (ushort16)((u + 0x7FFFu + ((u >> 16) & 1u)) >> 16);  // RNE
}
__device__ __forceinline__ void ws_store(float* p, float v) {
  __hip_atomic_store(p, v, __ATOMIC_RELAXED, __HIP_MEMORY_SCOPE_AGENT);
}
__device__ __forceinline__ float ws_load(const float* p) {
  return __hip_atomic_load(p, __ATOMIC_RELAXED, __HIP_MEMORY_SCOPE_AGENT);
}

// Prologue: convert key/value to bf16 (RNE) into workspace.
__global__ void kv_to_bf16(const float* __restrict__ key, const float* __restrict__ value,
                           ushort16* __restrict__ kbf, ushort16* __restrict__ vbf) {
  const size_t N4 = (size_t)BATCH * T_ENC * KVS / 4;
  for (size_t i = (size_t)blockIdx.x * blockDim.x + threadIdx.x; i < N4;
       i += (size_t)gridDim.x * blockDim.x) {
    float4 k4 = ((const float4*)key)[i];
    float4 v4 = ((const float4*)value)[i];
    ushort4 ko, vo;
    ko.x = f2bf(k4.x); ko.y = f2bf(k4.y); ko.z = f2bf(k4.z); ko.w = f2bf(k4.w);
    vo.x = f2bf(v4.x); vo.y = f2bf(v4.y); vo.z = f2bf(v4.z); vo.w = f2bf(v4.w);
    ((ushort4*)kbf)[i] = ko;
    ((ushort4*)vbf)[i] = vo;
  }
}

// 2 blocks per batch (same-XCD pair). Recurrent weights in registers,
// emb-gate table in LDS (round-5 structure). KV streamed as bf16 (BF16=true)
// or fp32 fallback if workspace is too small.
template <bool BF16>
__global__ __launch_bounds__(NTH, 4) void decoder_kernel(
    const float* __restrict__ key,    // B,T_ENC,KVS (fp32)
    const float* __restrict__ value,  // B,T_ENC,KVS (fp32)
    const ushort16* __restrict__ kbf, // bf16 key (if BF16)
    const ushort16* __restrict__ vbf, // bf16 value (if BF16)
    const int*   __restrict__ y,
    const float* __restrict__ emb,
    const float* __restrict__ W_ih,
    const float* __restrict__ W_hh,
    const float* __restrict__ b_ih,
    const float* __restrict__ b_hh,
    const float* __restrict__ b_cp,
    float* __restrict__ out,
    float* __restrict__ msgsA,        // [128][2 par][2 half][64]
    float* __restrict__ msgsB,        // [128][2 par][2 half][130]
    int*   __restrict__ flags)        // [128][2 par][2 phase][2 half]
{
  __shared__ float s_G[VOCAB * 256];
  __shared__ __align__(16) float s_emb[VOCAB * EMBED];
  __shared__ __align__(16) float s_rec[256];  // [ctx(128), h(128)]
  __shared__ float s_gates[256];
  __shared__ float s_c[64];
  __shared__ float s_attn[HALF_T];
  __shared__ float s_part[16][KVS];
  __shared__ float s_redm[16];
  __shared__ float s_reds[16];
  __shared__ float s_stats[2];
  __shared__ float s_biasloc[256];
  __shared__ float s_bcp[VOCAB];
  __shared__ int   s_y[MAX_LEN];

  const int bid  = blockIdx.x;
  const int half = (bid >> 3) & 1;              // partner shares bid%8 -> same XCD
  const int b    = (bid & 7) | ((bid >> 4) << 3);
  const int tid  = threadIdx.x;
  const int lane = tid & 63;
  const int wid  = tid >> 6;
  const int rloc = tid >> 2;
  const int q    = tid & 3;

  for (int i = tid; i < VOCAB * EMBED; i += NTH) s_emb[i] = emb[i];
  for (int i = tid; i < MAX_LEN; i += NTH)       s_y[i] = y[b * MAX_LEN + i];
  if (tid < VOCAB) s_bcp[tid] = b_cp[tid];
  if (tid < 256) {
    const int g2 = tid >> 6, j2 = tid & 63;
    const int gr2 = g2 * 128 + half * 64 + j2;
    s_biasloc[tid] = b_ih[gr2] + b_hh[gr2];
  }
  if (tid < KVS) {
    s_rec[tid] = value[(size_t)b * T_ENC * KVS + tid];  // ctx0 fp32 exact
    s_rec[128 + tid] = 0.f;
  }
  if (tid < 64) s_c[tid] = 0.f;
  __syncthreads();

  const int gate = rloc >> 6, jj = rloc & 63;
  const int grow = gate * 128 + half * 64 + jj;
  const float4* Wih4 = (const float4*)W_ih;
  const float4* Whh4 = (const float4*)W_hh;

  // G table (own 256 rows): W_emb*emb[v] + bias
  {
    float4 we[16];
    #pragma unroll
    for (int k = 0; k < 16; ++k) we[k] = Wih4[(size_t)grow * 96 + 4 * k + q];
    const float4* se4 = (const float4*)s_emb;
    for (int v = 0; v < VOCAB; ++v) {
      float a = 0.f;
      #pragma unroll
      for (int k = 0; k < 16; ++k) a += dot4(we[k], se4[v * 64 + 4 * k + q]);
      a += __shfl_xor(a, 1);
      a += __shfl_xor(a, 2);
      if (q == 0) s_G[v * 256 + rloc] = a + s_biasloc[rloc];
    }
  }

  // recurrent weights -> registers (64 VGPR/thread)
  float4 w4[16];
  #pragma unroll
  for (int k = 0; k < 8; ++k)
    w4[k] = Wih4[(size_t)grow * 96 + 64 + 4 * k + q];
  #pragma unroll
  for (int k = 8; k < 16; ++k)
    w4[k] = Whh4[(size_t)grow * 32 + 4 * (k - 8) + q];
  __syncthreads();

  const float*    keyb  = key   + (size_t)b * T_ENC * KVS + (size_t)half * HALF_T * KVS;
  const float*    valb  = value + (size_t)b * T_ENC * KVS + (size_t)half * HALF_T * KVS;
  const ushort16* kbfb  = kbf   + (size_t)b * T_ENC * KVS + (size_t)half * HALF_T * KVS;
  const ushort16* vbfb  = vbf   + (size_t)b * T_ENC * KVS + (size_t)half * HALF_T * KVS;
  const size_t PRED_SZ = (size_t)BATCH * MAX_LEN * VOCAB;
  const float4* sr4 = (const float4*)s_rec;

  for (int t = 0; t < MAX_LEN; ++t) {
    const int par = t & 1;
    float*       msgA_out = msgsA + (size_t)(((b * 2 + par) * 2) + half) * 64;
    const float* msgA_in  = msgsA + (size_t)(((b * 2 + par) * 2) + (half ^ 1)) * 64;
    float*       msgB_out = msgsB + (size_t)(((b * 2 + par) * 2) + half) * 130;
    const float* msgB_in  = msgsB + (size_t)(((b * 2 + par) * 2) + (half ^ 1)) * 130;
    int* flagA_out = flags + (((b * 2 + par) * 2 + 0) * 2) + half;
    int* flagA_in  = flags + (((b * 2 + par) * 2 + 0) * 2) + (half ^ 1);
    int* flagB_out = flags + (((b * 2 + par) * 2 + 1) * 2) + half;
    int* flagB_in  = flags + (((b * 2 + par) * 2 + 1) * 2) + (half ^ 1);

    // ---- gates ----
    {
      const float* Gsrc = (t == 0) ? s_biasloc : (s_G + s_y[t - 1] * 256);
      float a = 0.f;
      #pragma unroll
      for (int k = 0; k < 16; ++k) a += dot4(w4[k], sr4[4 * k + q]);
      a += __shfl_xor(a, 1);
      a += __shfl_xor(a, 2);
      if (q == 0) s_gates[rloc] = a + Gsrc[rloc];
    }
    __syncthreads();

    // ---- LSTM cell (own 64) + publish h ----
    if (tid < 64) {
      float ig = s_gates[tid], fg = s_gates[64 + tid];
      float gg = s_gates[128 + tid], og = s_gates[192 + tid];
      float si = 1.f / (1.f + __expf(-ig));
      float sf = 1.f / (1.f + __expf(-fg));
      float so = 1.f / (1.f + __expf(-og));
      float cn = sf * s_c[tid] + si * tanhf(gg);
      s_c[tid] = cn;
      float hn = so * tanhf(cn);
      s_rec[128 + half * 64 + tid] = hn;
      ws_store(msgA_out + tid, hn);
    }
    __syncthreads();
    // ---- handshake A ----
    if (tid == 0) {
      __hip_atomic_store(flagA_out, t + 1, __ATOMIC_RELEASE, __HIP_MEMORY_SCOPE_AGENT);
      while (__hip_atomic_load(flagA_in, __ATOMIC_ACQUIRE, __HIP_MEMORY_SCOPE_AGENT) < t + 1) {}
    }
    __syncthreads();
    if (tid < 64) s_rec[128 + (half ^ 1) * 64 + tid] = ws_load(msgA_in + tid);
    __syncthreads();

    // ---- energy over local 512 K-rows ----
    if constexpr (BF16) {
      const int sub = lane & 3, rl = lane >> 2;
      const float4* h4 = (const float4*)(s_rec + 128) + sub * 8;
      #pragma unroll
      for (int P = 0; P < 2; ++P) {
        const int row = wid * 32 + P * 16 + rl;
        const uint4* kr = (const uint4*)(kbfb + (size_t)row * KVS) + sub * 4;
        float a = 0.f;
        #pragma unroll
        for (int u = 0; u < 4; ++u) {
          const uint4 kw = kr[u];
          const float4 hA = h4[u * 2], hB = h4[u * 2 + 1];
          a += bf_lo(kw.x) * hA.x + bf_hi(kw.x) * hA.y
             + bf_lo(kw.y) * hA.z + bf_hi(kw.y) * hA.w
             + bf_lo(kw.z) * hB.x + bf_hi(kw.z) * hB.y
             + bf_lo(kw.w) * hB.z + bf_hi(kw.w) * hB.w;
        }
        a += __shfl_xor(a, 1);
        a += __shfl_xor(a, 2);
        if (sub == 0) s_attn[row] = a;
      }
    } else {
      const int sub = lane & 7, rl = lane >> 3;
      const float4* h4 = (const float4*)(s_rec + 128) + sub * 4;
      #pragma unroll
      for (int P = 0; P < 4; ++P) {
        const int row = wid * 32 + P * 8 + rl;
        const float4* kr = (const float4*)(keyb + (size_t)row * KVS + sub * 16);
        float a = dot4(kr[0], h4[0]) + dot4(kr[1], h4[1]) +
                  dot4(kr[2], h4[2]) + dot4(kr[3], h4[3]);
        a += __shfl_xor(a, 1);
        a += __shfl_xor(a, 2);
        a += __shfl_xor(a, 4);
        if (sub == 0) s_attn[row] = a;
      }
    }
    __syncthreads();

    // ---- local softmax stats ----
    float p_loc, m_loc, l_loc;
    {
      const float e = (tid < HALF_T) ? s_attn[tid] : -1e30f;
      float mm = e;
      #pragma unroll
      for (int o = 32; o; o >>= 1) mm = fmaxf(mm, __shfl_xor(mm, o));
      if (lane == 0) s_redm[wid] = mm;
      __syncthreads();
      m_loc = s_redm[0];
      #pragma unroll
      for (int w = 1; w < 16; ++w) m_loc = fmaxf(m_loc, s_redm[w]);
      float p = (tid < HALF_T) ? __expf(e - m_loc) : 0.f;
      p_loc = p;
      if (tid < HALF_T) s_attn[tid] = p;
      float ss = p;
      #pragma unroll
      for (int o = 32; o; o >>= 1) ss += __shfl_xor(ss, o);
      if (lane == 0) s_reds[wid] = ss;
      __syncthreads();
      l_loc = 0.f;
      #pragma unroll
      for (int w = 0; w < 16; ++w) l_loc += s_reds[w];
    }

    // ---- local ctx partial ----
    {
      const int kk = (tid & 63) * 2;
      const int part = tid >> 6;
      float ax = 0.f, ay = 0.f;
      if constexpr (BF16) {
        const uint32* vb = (const uint32*)(vbfb + (size_t)part * 32 * KVS) + (kk >> 1);
        #pragma unroll 8
        for (int q2 = 0; q2 < 32; ++q2) {
          const float w = s_attn[part * 32 + q2];
          const uint32 pv = vb[(size_t)q2 * 64];
          ax += w * bf_lo(pv); ay += w * bf_hi(pv);
        }
      } else {
        const float* vb = valb + (size_t)part * 32 * KVS + kk;
        #pragma unroll 8
        for (int q2 = 0; q2 < 32; ++q2) {
          const float w = s_attn[part * 32 + q2];
          const float2 v2 = *(const float2*)(vb + (size_t)q2 * KVS);
          ax += w * v2.x; ay += w * v2.y;
        }
      }
      s_part[part][kk] = ax; s_part[part][kk + 1] = ay;
    }
    __syncthreads();
    float ctxp = 0.f;
    if (tid < KVS) {
      #pragma unroll
      for (int p2 = 0; p2 < 16; ++p2) ctxp += s_part[p2][tid];
    }

    // ---- handshake B: merge softmax partials ----
    if (tid < KVS)      ws_store(msgB_out + 2 + tid, ctxp);
    if (tid == KVS)     ws_store(msgB_out + 0, m_loc);
    if (tid == KVS + 1) ws_store(msgB_out + 1, l_loc);
    __syncthreads();
    if (tid == 0) {
      __hip_atomic_store(flagB_out, t + 1, __ATOMIC_RELEASE, __HIP_MEMORY_SCOPE_AGENT);
      while (__hip_atomic_load(flagB_in, __ATOMIC_ACQUIRE, __HIP_MEMORY_SCOPE_AGENT) < t + 1) {}
      s_stats[0] = ws_load(msgB_in + 0);
      s_stats[1] = ws_load(msgB_in + 1);
    }
    __syncthreads();
    const float m_rem = s_stats[0], l_rem = s_stats[1];
    const float mA = half ? m_rem : m_loc, mB = half ? m_loc : m_rem;
    const float lA = half ? l_rem : l_loc, lB = half ? l_loc : l_rem;
    const float M  = fmaxf(mA, mB);
    const float wA = __expf(mA - M), wB = __expf(mB - M);
    const float S  = wA * lA + wB * lB;
    const float invS = 1.f / S;
    const float w_own = half ? wB : wA;
    if (tid < KVS) {
      const float cr = ws_load(msgB_in + 2 + tid);
      const float cA = half ? cr : ctxp, cB = half ? ctxp : cr;
      s_rec[tid] = (wA * cA + wB * cB) * invS;
    }
    if (b == 0 && tid < HALF_T) {
      out[PRED_SZ + (size_t)t * T_ENC + half * HALF_T + tid] = p_loc * w_own * invS;
    }
    __syncthreads();

    // ---- pred (half 0 only) ----
    if (half == 0 && tid < 480) {
      const int v = tid >> 4, sl = tid & 15;
      float acc = 0.f;
      #pragma unroll
      for (int q2 = 0; q2 < 16; ++q2) {
        const int e2 = sl * 16 + q2;
        const float oc = (e2 < KVS) ? s_rec[128 + e2] : s_rec[e2 - KVS];
        acc += oc * s_emb[v * EMBED + e2];
      }
      #pragma unroll
      for (int o = 8; o; o >>= 1) acc += __shfl_xor(acc, o);
      if (sl == 0) out[((size_t)b * MAX_LEN + t) * VOCAB + v] = acc + s_bcp[v];
    }
  }
}

extern "C" void kernel_launch(void* const* d_in, const int* in_sizes, int n_in,
                              void* d_out, int out_size, void* d_ws, size_t ws_size,
                              hipStream_t stream) {
  const float* key   = (const float*)d_in[0];
  const float* value = (const float*)d_in[1];
  const int*   y     = (const int*)d_in[3];
  const float* emb   = (const float*)d_in[4];
  const float* W_ih  = (const float*)d_in[5];
  const float* W_hh  = (const float*)d_in[6];
  const float* b_ih  = (const float*)d_in[7];
  const float* b_hh  = (const float*)d_in[8];
  const float* b_cp  = (const float*)d_in[9];
  float* out = (float*)d_out;

  int*   flags = (int*)d_ws;
  float* msgsA = (float*)((char*)d_ws + 8192);
  float* msgsB = (float*)((char*)d_ws + 8192 + 131072);

  const size_t KVN  = (size_t)BATCH * T_ENC * KVS;           // 16.7M elems
  const size_t BF_OFF = 1u << 20;                            // 1 MB aligned
  const size_t need = BF_OFF + 2 * KVN * sizeof(ushort16);   // ~68 MB
  ushort16* kbf = (ushort16*)((char*)d_ws + BF_OFF);
  ushort16* vbf = kbf + KVN;

  hipMemsetAsync(d_ws, 0, 8192, stream);
  if (ws_size >= need) {
    kv_to_bf16<<<2048, 256, 0, stream>>>(key, value, kbf, vbf);
    decoder_kernel<true><<<2 * BATCH, NTH, 0, stream>>>(
        key, value, kbf, vbf, y, emb, W_ih, W_hh, b_ih, b_hh, b_cp, out,
        msgsA, msgsB, flags);
  } else {
    decoder_kernel<false><<<2 * BATCH, NTH, 0, stream>>>(
        key, value, kbf, vbf, y, emb, W_ih, W_hh, b_ih, b_hh, b_cp, out,
        msgsA, msgsB, flags);
  }
}

// Round 8
// 4783.755 us; speedup vs baseline: 2.3775x; 2.3775x over previous
//
#include <hip/hip_runtime.h>

#define VOCAB   30
#define EMBED   256
#define KVS     128
#define BATCH   128
#define T_ENC   1024
#define MAX_LEN 250
#define NTH     1024
#define HALF_T  512

typedef unsigned int uint32;
typedef unsigned short ushort16;

__device__ __forceinline__ float dot4(float4 a, float4 b) {
  return a.x * b.x + a.y * b.y + a.z * b.z + a.w * b.w;
}
__device__ __forceinline__ float bf_lo(uint32 u) { return __uint_as_float(u << 16); }
__device__ __forceinline__ float bf_hi(uint32 u) { return __uint_as_float(u & 0xffff0000u); }
__device__ __forceinline__ ushort16 f2bf(float f) {
  uint32 u = __float_as_uint(f);
  return (ushort16)((u + 0x7FFFu + ((u >> 16) & 1u)) >> 16);  // RNE
}
__device__ __forceinline__ uint32 pack2(float a, float b) {
  return (uint32)f2bf(a) | ((uint32)f2bf(b) << 16);
}
__device__ __forceinline__ void ws_store(float* p, float v) {
  __hip_atomic_store(p, v, __ATOMIC_RELAXED, __HIP_MEMORY_SCOPE_AGENT);
}
__device__ __forceinline__ float ws_load(const float* p) {
  return __hip_atomic_load(p, __ATOMIC_RELAXED, __HIP_MEMORY_SCOPE_AGENT);
}

// 2 blocks per batch (same-XCD pair). Zero steady-state global traffic:
//  - recurrent weights: 64 VGPR/thread (fp32)
//  - K half-tile: bf16 packed in 32 VGPR/thread
//  - V half-tile: bf16 packed in 128 KB LDS
//  - emb-gate table G: bf16 in LDS (j-split rows)
// Per step: 2 flash-style handshakes (A: h halves, B: softmax/ctx merge).
__global__ __launch_bounds__(NTH, 4) void decoder_kernel(
    const float* __restrict__ key,    // B,T_ENC,KVS (fp32)
    const float* __restrict__ value,  // B,T_ENC,KVS (fp32)
    const int*   __restrict__ y,
    const float* __restrict__ emb,    // VOCAB,EMBED (read per-step from L2)
    const float* __restrict__ W_ih,
    const float* __restrict__ W_hh,
    const float* __restrict__ b_ih,
    const float* __restrict__ b_hh,
    const float* __restrict__ b_cp,
    float* __restrict__ out,
    float* __restrict__ msgsA,        // [128][2 par][2 half][64]
    float* __restrict__ msgsB,        // [128][2 par][2 half][130]
    int*   __restrict__ flags)        // [128][2 par][2 phase][2 half]
{
  __shared__ uint32 s_V[HALF_T * 64];          // 128 KB: V bf16 pairs; emb scratch in prologue
  __shared__ ushort16 s_G16[VOCAB * 256];      // 15 KB: gate-emb table bf16
  __shared__ __align__(16) float s_rec[256];   // [ctx(128), h(128)]
  __shared__ float s_gates[256];
  __shared__ float s_c[64];
  __shared__ float s_attn[HALF_T];
  __shared__ float s_part[16][KVS];            // 8 KB
  __shared__ float s_redm[16];
  __shared__ float s_reds[16];
  __shared__ float s_stats[2];
  __shared__ float s_biasloc[256];
  __shared__ float s_bcp[VOCAB];
  __shared__ int   s_y[MAX_LEN];

  const int bid  = blockIdx.x;
  const int half = (bid >> 3) & 1;             // partner shares bid%8 -> same XCD
  const int b    = (bid & 7) | ((bid >> 4) << 3);
  const int tid  = threadIdx.x;
  const int lane = tid & 63;
  const int wid  = tid >> 6;
  const int rloc = tid >> 2;                   // gate row 0..255 (j-split)
  const int q    = tid & 3;

  const float* keyb = key   + (size_t)b * T_ENC * KVS + (size_t)half * HALF_T * KVS;
  const float* valb = value + (size_t)b * T_ENC * KVS + (size_t)half * HALF_T * KVS;

  // ---- prologue A: emb scratch + small state ----
  float* s_scr = (float*)s_V;                  // borrow V space for fp32 emb
  for (int i = tid; i < VOCAB * EMBED; i += NTH) s_scr[i] = emb[i];
  for (int i = tid; i < MAX_LEN; i += NTH)       s_y[i] = y[b * MAX_LEN + i];
  if (tid < VOCAB) s_bcp[tid] = b_cp[tid];
  if (tid < 256) {
    const int g2 = tid >> 6, j2 = tid & 63;
    const int gr2 = g2 * 128 + half * 64 + j2;
    s_biasloc[tid] = b_ih[gr2] + b_hh[gr2];
  }
  if (tid < KVS) {
    s_rec[tid] = value[(size_t)b * T_ENC * KVS + tid];  // ctx0 fp32 exact
    s_rec[128 + tid] = 0.f;
  }
  if (tid < 64) s_c[tid] = 0.f;
  __syncthreads();

  const int gate = rloc >> 6, jj = rloc & 63;
  const int grow = gate * 128 + half * 64 + jj;
  const float4* Wih4 = (const float4*)W_ih;    // row stride 96 float4
  const float4* Whh4 = (const float4*)W_hh;    // row stride 32 float4

  // ---- prologue B: G table (bf16), reads emb from scratch ----
  {
    float4 we[16];
    #pragma unroll
    for (int k = 0; k < 16; ++k) we[k] = Wih4[(size_t)grow * 96 + 4 * k + q];
    const float4* se4 = (const float4*)s_scr;
    for (int v = 0; v < VOCAB; ++v) {
      float a = 0.f;
      #pragma unroll
      for (int k = 0; k < 16; ++k) a += dot4(we[k], se4[v * 64 + 4 * k + q]);
      a += __shfl_xor(a, 1);
      a += __shfl_xor(a, 2);
      if (q == 0) s_G16[v * 256 + rloc] = f2bf(a + s_biasloc[rloc]);
    }
  }
  __syncthreads();   // emb scratch dead; s_V reusable

  // ---- prologue C: recurrent weights -> 64 VGPR ----
  float4 w4[16];
  #pragma unroll
  for (int k = 0; k < 8; ++k)
    w4[k] = Wih4[(size_t)grow * 96 + 64 + 4 * k + q];     // ctx cols of W_ih
  #pragma unroll
  for (int k = 8; k < 16; ++k)
    w4[k] = Whh4[(size_t)grow * 32 + 4 * (k - 8) + q];    // W_hh

  // ---- prologue D: K half-tile -> 32 VGPR (bf16 pairs) ----
  // thread t: row r=t>>1, cols (t&1)*64..+63
  uint4 ku[8];
  {
    const float4* kg = (const float4*)(keyb + (size_t)(tid >> 1) * KVS + (tid & 1) * 64);
    #pragma unroll 2
    for (int i = 0; i < 8; ++i) {
      const float4 a0 = kg[2 * i], a1 = kg[2 * i + 1];
      ku[i].x = pack2(a0.x, a0.y); ku[i].y = pack2(a0.z, a0.w);
      ku[i].z = pack2(a1.x, a1.y); ku[i].w = pack2(a1.z, a1.w);
    }
  }

  // ---- prologue E: V half-tile -> LDS (bf16 pairs, [row][colpair]) ----
  for (int idx = tid; idx < HALF_T * 64; idx += NTH) {
    const int row = idx >> 6, cp = idx & 63;
    const float2 v2 = *(const float2*)(valb + (size_t)row * KVS + 2 * cp);
    s_V[idx] = pack2(v2.x, v2.y);
  }
  __syncthreads();

  const size_t PRED_SZ = (size_t)BATCH * MAX_LEN * VOCAB;
  const float4* sr4 = (const float4*)s_rec;

  for (int t = 0; t < MAX_LEN; ++t) {
    const int par = t & 1;
    float*       msgA_out = msgsA + (size_t)(((b * 2 + par) * 2) + half) * 64;
    const float* msgA_in  = msgsA + (size_t)(((b * 2 + par) * 2) + (half ^ 1)) * 64;
    float*       msgB_out = msgsB + (size_t)(((b * 2 + par) * 2) + half) * 130;
    const float* msgB_in  = msgsB + (size_t)(((b * 2 + par) * 2) + (half ^ 1)) * 130;
    int* flagA_out = flags + (((b * 2 + par) * 2 + 0) * 2) + half;
    int* flagA_in  = flags + (((b * 2 + par) * 2 + 0) * 2) + (half ^ 1);
    int* flagB_out = flags + (((b * 2 + par) * 2 + 1) * 2) + half;
    int* flagB_in  = flags + (((b * 2 + par) * 2 + 1) * 2) + (half ^ 1);

    // ---- gates: G[yprev] + Wreg * [ctx,h] ----
    {
      float a = 0.f;
      #pragma unroll
      for (int k = 0; k < 16; ++k) a += dot4(w4[k], sr4[4 * k + q]);
      a += __shfl_xor(a, 1);
      a += __shfl_xor(a, 2);
      if (q == 0) {
        const float gb = (t == 0)
            ? s_biasloc[rloc]
            : __uint_as_float(((uint32)s_G16[s_y[t - 1] * 256 + rloc]) << 16);
        s_gates[rloc] = a + gb;
      }
    }
    __syncthreads();

    // ---- LSTM cell (own 64) + publish h ----
    if (tid < 64) {
      float ig = s_gates[tid], fg = s_gates[64 + tid];
      float gg = s_gates[128 + tid], og = s_gates[192 + tid];
      float si = 1.f / (1.f + __expf(-ig));
      float sf = 1.f / (1.f + __expf(-fg));
      float so = 1.f / (1.f + __expf(-og));
      float cn = sf * s_c[tid] + si * tanhf(gg);
      s_c[tid] = cn;
      float hn = so * tanhf(cn);
      s_rec[128 + half * 64 + tid] = hn;
      ws_store(msgA_out + tid, hn);
    }
    __syncthreads();
    // ---- handshake A: exchange h halves ----
    if (tid == 0) {
      __hip_atomic_store(flagA_out, t + 1, __ATOMIC_RELEASE, __HIP_MEMORY_SCOPE_AGENT);
      while (__hip_atomic_load(flagA_in, __ATOMIC_ACQUIRE, __HIP_MEMORY_SCOPE_AGENT) < t + 1) {}
    }
    __syncthreads();
    if (tid < 64) s_rec[128 + (half ^ 1) * 64 + tid] = ws_load(msgA_in + tid);
    __syncthreads();

    // ---- energy: K from registers, h from LDS ----
    {
      const int r = tid >> 1, kh = tid & 1;
      const float4* h4 = (const float4*)(s_rec + 128) + kh * 16;
      float a = 0.f;
      #pragma unroll 2
      for (int i = 0; i < 8; ++i) {
        const uint4 kw = ku[i];
        const float4 hA = h4[2 * i], hB = h4[2 * i + 1];
        a += bf_lo(kw.x) * hA.x + bf_hi(kw.x) * hA.y
           + bf_lo(kw.y) * hA.z + bf_hi(kw.y) * hA.w
           + bf_lo(kw.z) * hB.x + bf_hi(kw.z) * hB.y
           + bf_lo(kw.w) * hB.z + bf_hi(kw.w) * hB.w;
      }
      a += __shfl_xor(a, 1);
      if (kh == 0) s_attn[r] = a;
    }
    __syncthreads();

    // ---- local softmax stats ----
    float p_loc, m_loc, l_loc;
    {
      const float e = (tid < HALF_T) ? s_attn[tid] : -1e30f;
      float mm = e;
      #pragma unroll
      for (int o = 32; o; o >>= 1) mm = fmaxf(mm, __shfl_xor(mm, o));
      if (lane == 0) s_redm[wid] = mm;
      __syncthreads();
      m_loc = s_redm[0];
      #pragma unroll
      for (int w = 1; w < 16; ++w) m_loc = fmaxf(m_loc, s_redm[w]);
      float p = (tid < HALF_T) ? __expf(e - m_loc) : 0.f;
      p_loc = p;
      if (tid < HALF_T) s_attn[tid] = p;
      float ss = p;
      #pragma unroll
      for (int o = 32; o; o >>= 1) ss += __shfl_xor(ss, o);
      if (lane == 0) s_reds[wid] = ss;
      __syncthreads();
      l_loc = 0.f;
      #pragma unroll
      for (int w = 0; w < 16; ++w) l_loc += s_reds[w];
    }

    // ---- local ctx partial: V from LDS ----
    // wave w owns rows {w, w+16, ..., w+496}; lane covers colpair cp
    {
      const int cp = tid & 63, ch = wid;
      float ax = 0.f, ay = 0.f;
      #pragma unroll 8
      for (int r2 = 0; r2 < 32; ++r2) {
        const int row = ch + (r2 << 4);
        const float w = s_attn[row];
        const uint32 pv = s_V[(row << 6) + cp];
        ax += w * bf_lo(pv); ay += w * bf_hi(pv);
      }
      s_part[ch][2 * cp] = ax; s_part[ch][2 * cp + 1] = ay;
    }
    __syncthreads();
    float ctxp = 0.f;
    if (tid < KVS) {
      #pragma unroll
      for (int p2 = 0; p2 < 16; ++p2) ctxp += s_part[p2][tid];
    }

    // ---- handshake B: merge softmax partials ----
    if (tid < KVS)      ws_store(msgB_out + 2 + tid, ctxp);
    if (tid == KVS)     ws_store(msgB_out + 0, m_loc);
    if (tid == KVS + 1) ws_store(msgB_out + 1, l_loc);
    __syncthreads();
    if (tid == 0) {
      __hip_atomic_store(flagB_out, t + 1, __ATOMIC_RELEASE, __HIP_MEMORY_SCOPE_AGENT);
      while (__hip_atomic_load(flagB_in, __ATOMIC_ACQUIRE, __HIP_MEMORY_SCOPE_AGENT) < t + 1) {}
      s_stats[0] = ws_load(msgB_in + 0);
      s_stats[1] = ws_load(msgB_in + 1);
    }
    __syncthreads();
    const float m_rem = s_stats[0], l_rem = s_stats[1];
    const float mA = half ? m_rem : m_loc, mB = half ? m_loc : m_rem;
    const float lA = half ? l_rem : l_loc, lB = half ? l_loc : l_rem;
    const float M  = fmaxf(mA, mB);
    const float wA = __expf(mA - M), wB = __expf(mB - M);
    const float S  = wA * lA + wB * lB;
    const float invS = 1.f / S;
    const float w_own = half ? wB : wA;
    if (tid < KVS) {
      const float cr = ws_load(msgB_in + 2 + tid);
      const float cA = half ? cr : ctxp, cB = half ? ctxp : cr;
      s_rec[tid] = (wA * cA + wB * cB) * invS;
    }
    if (b == 0 && tid < HALF_T) {
      out[PRED_SZ + (size_t)t * T_ENC + half * HALF_T + tid] = p_loc * w_own * invS;
    }
    __syncthreads();

    // ---- pred (half 0 only), emb from global (L2-hot 30 KB) ----
    if (half == 0 && tid < 480) {
      const int v = tid >> 4, sl = tid & 15;
      const float4* eg = (const float4*)(emb + v * EMBED + sl * 16);
      const float* oc = (sl < 8) ? (s_rec + 128 + sl * 16) : (s_rec + (sl - 8) * 16);
      float acc = dot4(eg[0], *(const float4*)(oc))
                + dot4(eg[1], *(const float4*)(oc + 4))
                + dot4(eg[2], *(const float4*)(oc + 8))
                + dot4(eg[3], *(const float4*)(oc + 12));
      #pragma unroll
      for (int o = 8; o; o >>= 1) acc += __shfl_xor(acc, o);
      if (sl == 0) out[((size_t)b * MAX_LEN + t) * VOCAB + v] = acc + s_bcp[v];
    }
  }
}

extern "C" void kernel_launch(void* const* d_in, const int* in_sizes, int n_in,
                              void* d_out, int out_size, void* d_ws, size_t ws_size,
                              hipStream_t stream) {
  const float* key   = (const float*)d_in[0];
  const float* value = (const float*)d_in[1];
  // d_in[2] = encoder_len : unused by the reference computation
  const int*   y     = (const int*)d_in[3];
  const float* emb   = (const float*)d_in[4];
  const float* W_ih  = (const float*)d_in[5];
  const float* W_hh  = (const float*)d_in[6];
  const float* b_ih  = (const float*)d_in[7];
  const float* b_hh  = (const float*)d_in[8];
  const float* b_cp  = (const float*)d_in[9];
  float* out = (float*)d_out;

  int*   flags = (int*)d_ws;                               // 4 KB used
  float* msgsA = (float*)((char*)d_ws + 8192);             // 128 KB
  float* msgsB = (float*)((char*)d_ws + 8192 + 131072);    // 260 KB

  hipMemsetAsync(d_ws, 0, 8192, stream);
  decoder_kernel<<<2 * BATCH, NTH, 0, stream>>>(key, value, y, emb, W_ih, W_hh,
                                                b_ih, b_hh, b_cp, out,
                                                msgsA, msgsB, flags);
}

// Round 13
// 4222.112 us; speedup vs baseline: 2.6938x; 1.1330x over previous
//
#include <hip/hip_runtime.h>

#define VOCAB   30
#define EMBED   256
#define KVS     128
#define BATCH   128
#define T_ENC   1024
#define MAX_LEN 250
#define NTH     1024
#define HALF_T  512

typedef unsigned int uint32;
typedef unsigned short u16;

__device__ __forceinline__ float dot4(float4 a, float4 b) {
  return a.x * b.x + a.y * b.y + a.z * b.z + a.w * b.w;
}
__device__ __forceinline__ float bf_lo(uint32 u) { return __uint_as_float(u << 16); }
__device__ __forceinline__ float bf_hi(uint32 u) { return __uint_as_float(u & 0xffff0000u); }
__device__ __forceinline__ u16 f2bf(float f) {
  uint32 u = __float_as_uint(f);
  return (u16)((u + 0x7FFFu + ((u >> 16) & 1u)) >> 16);  // RNE
}
__device__ __forceinline__ uint32 pack2(float a, float b) {
  return (uint32)f2bf(a) | ((uint32)f2bf(b) << 16);
}
// All cross-block traffic uses RELAXED agent-scope atomics: they execute at the
// coherence point (proven coherent cross-block in rounds 4-8), and avoid the
// per-access L2-invalidate that ACQUIRE emits on gfx950.
__device__ __forceinline__ void ws_store(float* p, float v) {
  __hip_atomic_store(p, v, __ATOMIC_RELAXED, __HIP_MEMORY_SCOPE_AGENT);
}
__device__ __forceinline__ float ws_load(const float* p) {
  return __hip_atomic_load(p, __ATOMIC_RELAXED, __HIP_MEMORY_SCOPE_AGENT);
}
__device__ __forceinline__ void flag_store(int* p, int v) {
  __hip_atomic_store(p, v, __ATOMIC_RELAXED, __HIP_MEMORY_SCOPE_AGENT);
}
__device__ __forceinline__ int flag_load(const int* p) {
  return __hip_atomic_load(p, __ATOMIC_RELAXED, __HIP_MEMORY_SCOPE_AGENT);
}

// G_tab[v][r] = W_ih[r, 0:256] . emb[v] + b_ih[r] + b_hh[r]  (v = VOCAB row: bias only)
// Batch-independent: built once, read L2-hot by all blocks every step.
__global__ void build_G(const float* __restrict__ emb, const float* __restrict__ W_ih,
                        const float* __restrict__ b_ih, const float* __restrict__ b_hh,
                        float* __restrict__ G) {
  const int v = blockIdx.x;    // 0..VOCAB (VOCAB = bias row)
  const int r = threadIdx.x;   // 0..511
  float acc = b_ih[r] + b_hh[r];
  if (v < VOCAB) {
    const float4* w = (const float4*)(W_ih + (size_t)r * 384);
    const float4* e = (const float4*)(emb + (size_t)v * EMBED);
    #pragma unroll 8
    for (int k = 0; k < 64; ++k) acc += dot4(w[k], e[k]);
  }
  G[v * 512 + r] = acc;
}

// 2 blocks per batch (pair swizzled to share bid%8). Pair-redundant LSTM:
// both blocks compute all 512 gates (bf16 weights, 64 VGPR) -> identical h,
// so the h-exchange handshake is gone. K half-tile in 32 VGPR (bf16),
// V half-tile in 128 KB LDS (bf16). ONE relaxed handshake per step.
__global__ __launch_bounds__(NTH, 4) void decoder_kernel(
    const float* __restrict__ key,    // B,T_ENC,KVS
    const float* __restrict__ value,  // B,T_ENC,KVS
    const int*   __restrict__ y,
    const float* __restrict__ emb,    // pred reads it from L2 per step
    const float* __restrict__ W_ih,
    const float* __restrict__ W_hh,
    const float* __restrict__ b_cp,
    const float* __restrict__ G_tab,  // [VOCAB+1][512] fp32
    float* __restrict__ out,          // preds B*250*30, then attn 250*1024
    float* __restrict__ msgs,         // [128][2 par][2 half][130]
    int*   __restrict__ flags)        // [128][2 par][2 half]
{
  __shared__ uint32 s_V[HALF_T * 64];          // 128 KB bf16 pairs
  __shared__ __align__(16) float s_rec[256];   // [ctx(128), h(128)]
  __shared__ float s_gates[512];
  __shared__ float s_attn[512];
  __shared__ float s_c[128];
  __shared__ float s_part[16][KVS];            // 8 KB
  __shared__ float s_redm[16];
  __shared__ float s_reds[16];
  __shared__ float s_stats[2];
  __shared__ float s_bcp[VOCAB];
  __shared__ int   s_y[MAX_LEN];

  const int bid  = blockIdx.x;
  const int half = (bid >> 3) & 1;             // pair partner differs only in this bit
  const int b    = (bid & 7) | ((bid >> 4) << 3);
  const int tid  = threadIdx.x;
  const int lane = tid & 63;
  const int wid  = tid >> 6;
  const int rr   = tid >> 1;                   // row 0..511 (gates & energy)
  const int cc   = tid & 1;                    // column half

  const float* keyb = key   + (size_t)b * T_ENC * KVS + (size_t)half * HALF_T * KVS;
  const float* valb = value + (size_t)b * T_ENC * KVS + (size_t)half * HALF_T * KVS;

  // ---- prologue: small state ----
  for (int i = tid; i < MAX_LEN; i += NTH) s_y[i] = y[b * MAX_LEN + i];
  if (tid < VOCAB) s_bcp[tid] = b_cp[tid];
  if (tid < KVS) {
    s_rec[tid] = value[(size_t)b * T_ENC * KVS + tid];  // ctx0 fp32 exact
    s_rec[128 + tid] = 0.f;                             // h0
  }
  if (tid < 128) s_c[tid] = 0.f;

  // ---- prologue: full gate weights, bf16, 64 VGPR ----
  // thread (rr, cc): row rr, cols cc*128..+127 of [ctx | h]
  uint4 gw[16];
  {
    const float4* p = (cc == 0) ? (const float4*)(W_ih + (size_t)rr * 384 + 256)
                                : (const float4*)(W_hh + (size_t)rr * 128);
    #pragma unroll 4
    for (int k = 0; k < 16; ++k) {
      const float4 a0 = p[2 * k], a1 = p[2 * k + 1];
      gw[k].x = pack2(a0.x, a0.y); gw[k].y = pack2(a0.z, a0.w);
      gw[k].z = pack2(a1.x, a1.y); gw[k].w = pack2(a1.z, a1.w);
    }
  }

  // ---- prologue: K half-tile -> 32 VGPR (bf16 pairs) ----
  uint4 ku[8];
  {
    const float4* kg = (const float4*)(keyb + (size_t)rr * KVS + cc * 64);
    #pragma unroll 2
    for (int i = 0; i < 8; ++i) {
      const float4 a0 = kg[2 * i], a1 = kg[2 * i + 1];
      ku[i].x = pack2(a0.x, a0.y); ku[i].y = pack2(a0.z, a0.w);
      ku[i].z = pack2(a1.x, a1.y); ku[i].w = pack2(a1.z, a1.w);
    }
  }

  // ---- prologue: V half-tile -> LDS (bf16 pairs, [row][colpair]) ----
  for (int idx = tid; idx < HALF_T * 64; idx += NTH) {
    const int row = idx >> 6, cp = idx & 63;
    const float2 v2 = *(const float2*)(valb + (size_t)row * KVS + 2 * cp);
    s_V[idx] = pack2(v2.x, v2.y);
  }
  __syncthreads();

  const size_t PRED_SZ = (size_t)BATCH * MAX_LEN * VOCAB;
  const float4* sr4 = (const float4*)s_rec;

  for (int t = 0; t < MAX_LEN; ++t) {
    const int par = t & 1;
    float*       msg_out = msgs + (size_t)(((b * 2 + par) * 2) + half) * 130;
    const float* msg_in  = msgs + (size_t)(((b * 2 + par) * 2) + (half ^ 1)) * 130;
    int* flag_out = flags + ((b * 2 + par) * 2) + half;
    int* flag_in  = flags + ((b * 2 + par) * 2) + (half ^ 1);

    // ---- gates: G_tab[yprev] + Wbf16 * [ctx,h]  (redundant across pair) ----
    {
      const int yprev = (t == 0) ? VOCAB : s_y[t - 1];
      const float gb = G_tab[yprev * 512 + rr];   // issued early, L2-hot
      float a = 0.f;
      #pragma unroll
      for (int k = 0; k < 16; ++k) {
        const uint4 w = gw[k];
        const float4 xA = sr4[cc * 32 + 2 * k], xB = sr4[cc * 32 + 2 * k + 1];
        a += bf_lo(w.x) * xA.x + bf_hi(w.x) * xA.y
           + bf_lo(w.y) * xA.z + bf_hi(w.y) * xA.w
           + bf_lo(w.z) * xB.x + bf_hi(w.z) * xB.y
           + bf_lo(w.w) * xB.z + bf_hi(w.w) * xB.w;
      }
      a += __shfl_xor(a, 1);
      if (cc == 0) s_gates[rr] = a + gb;
    }
    __syncthreads();

    // ---- LSTM cell: all 128 cells, both blocks (identical bits) ----
    if (tid < 128) {
      const float ig = s_gates[tid],       fg = s_gates[128 + tid];
      const float gg = s_gates[256 + tid], og = s_gates[384 + tid];
      const float si = 1.f / (1.f + __expf(-ig));
      const float sf = 1.f / (1.f + __expf(-fg));
      const float so = 1.f / (1.f + __expf(-og));
      const float cn = sf * s_c[tid] + si * tanhf(gg);
      s_c[tid] = cn;
      s_rec[128 + tid] = so * tanhf(cn);
    }
    __syncthreads();

    // ---- energy: K regs x h LDS, rows 0..511 ----
    {
      const float4* h4 = (const float4*)(s_rec + 128) + cc * 16;
      float a = 0.f;
      #pragma unroll 2
      for (int i = 0; i < 8; ++i) {
        const uint4 kw = ku[i];
        const float4 hA = h4[2 * i], hB = h4[2 * i + 1];
        a += bf_lo(kw.x) * hA.x + bf_hi(kw.x) * hA.y
           + bf_lo(kw.y) * hA.z + bf_hi(kw.y) * hA.w
           + bf_lo(kw.z) * hB.x + bf_hi(kw.z) * hB.y
           + bf_lo(kw.w) * hB.z + bf_hi(kw.w) * hB.w;
      }
      a += __shfl_xor(a, 1);
      if (cc == 0) s_attn[rr] = a;
    }
    __syncthreads();

    // ---- local softmax stats ----
    float p_loc, m_loc, l_loc;
    {
      const float e = (tid < HALF_T) ? s_attn[tid] : -1e30f;
      float mm = e;
      #pragma unroll
      for (int o = 32; o; o >>= 1) mm = fmaxf(mm, __shfl_xor(mm, o));
      if (lane == 0) s_redm[wid] = mm;
      __syncthreads();
      m_loc = s_redm[0];
      #pragma unroll
      for (int w = 1; w < 16; ++w) m_loc = fmaxf(m_loc, s_redm[w]);
      const float p = (tid < HALF_T) ? __expf(e - m_loc) : 0.f;
      p_loc = p;
      if (tid < HALF_T) s_attn[tid] = p;
      float ss = p;
      #pragma unroll
      for (int o = 32; o; o >>= 1) ss += __shfl_xor(ss, o);
      if (lane == 0) s_reds[wid] = ss;
      __syncthreads();
      l_loc = 0.f;
      #pragma unroll
      for (int w = 0; w < 16; ++w) l_loc += s_reds[w];
    }

    // ---- local ctx partial: V from LDS ----
    {
      const int cp = tid & 63, ch = wid;
      float ax = 0.f, ay = 0.f;
      #pragma unroll 8
      for (int r2 = 0; r2 < 32; ++r2) {
        const int row = ch + (r2 << 4);
        const float w = s_attn[row];
        const uint32 pv = s_V[(row << 6) + cp];
        ax += w * bf_lo(pv); ay += w * bf_hi(pv);
      }
      s_part[ch][2 * cp] = ax; s_part[ch][2 * cp + 1] = ay;
    }
    __syncthreads();
    float ctxp = 0.f;
    if (tid < KVS) {
      #pragma unroll
      for (int p2 = 0; p2 < 16; ++p2) ctxp += s_part[p2][tid];
    }

    // ---- single handshake: merge softmax partials (all relaxed) ----
    if (tid < KVS)      ws_store(msg_out + 2 + tid, ctxp);
    if (tid == KVS)     ws_store(msg_out + 0, m_loc);
    if (tid == KVS + 1) ws_store(msg_out + 1, l_loc);
    __syncthreads();   // vmcnt drained before barrier -> msgs committed
    if (tid == 0) {
      flag_store(flag_out, t + 1);
      while (flag_load(flag_in) < t + 1) {}
      s_stats[0] = ws_load(msg_in + 0);
      s_stats[1] = ws_load(msg_in + 1);
    }
    __syncthreads();
    const float m_rem = s_stats[0], l_rem = s_stats[1];
    // fixed half-order merge => bitwise-identical ctx in both blocks
    const float mA = half ? m_rem : m_loc, mB = half ? m_loc : m_rem;
    const float lA = half ? l_rem : l_loc, lB = half ? l_loc : l_rem;
    const float M  = fmaxf(mA, mB);
    const float wA = __expf(mA - M), wB = __expf(mB - M);
    const float S  = wA * lA + wB * lB;
    const float invS = 1.f / S;
    const float w_own = half ? wB : wA;
    if (tid < KVS) {
      const float cr = ws_load(msg_in + 2 + tid);
      const float cA = half ? cr : ctxp, cB = half ? ctxp : cr;
      s_rec[tid] = (wA * cA + wB * cB) * invS;
    }
    if (b == 0 && tid < HALF_T) {
      out[PRED_SZ + (size_t)t * T_ENC + half * HALF_T + tid] = p_loc * w_own * invS;
    }
    __syncthreads();

    // ---- pred (half 0 only), emb from L2 ----
    if (half == 0 && tid < 480) {
      const int v = tid >> 4, sl = tid & 15;
      const float4* eg = (const float4*)(emb + v * EMBED + sl * 16);
      const float* oc = (sl < 8) ? (s_rec + 128 + sl * 16) : (s_rec + (sl - 8) * 16);
      float acc = dot4(eg[0], *(const float4*)(oc))
                + dot4(eg[1], *(const float4*)(oc + 4))
                + dot4(eg[2], *(const float4*)(oc + 8))
                + dot4(eg[3], *(const float4*)(oc + 12));
      #pragma unroll
      for (int o = 8; o; o >>= 1) acc += __shfl_xor(acc, o);
      if (sl == 0) out[((size_t)b * MAX_LEN + t) * VOCAB + v] = acc + s_bcp[v];
    }
    // pred stragglers are protected by the next iteration's gates barrier.
  }
}

extern "C" void kernel_launch(void* const* d_in, const int* in_sizes, int n_in,
                              void* d_out, int out_size, void* d_ws, size_t ws_size,
                              hipStream_t stream) {
  const float* key   = (const float*)d_in[0];
  const float* value = (const float*)d_in[1];
  // d_in[2] = encoder_len : unused by the reference computation
  const int*   y     = (const int*)d_in[3];
  const float* emb   = (const float*)d_in[4];
  const float* W_ih  = (const float*)d_in[5];
  const float* W_hh  = (const float*)d_in[6];
  const float* b_ih  = (const float*)d_in[7];
  const float* b_hh  = (const float*)d_in[8];
  const float* b_cp  = (const float*)d_in[9];
  float* out = (float*)d_out;

  int*   flags = (int*)d_ws;                            // 2 KB used (8 KB zeroed)
  float* msgs  = (float*)((char*)d_ws + 8192);          // 128*2*2*130*4 = 260 KB
  float* G_tab = (float*)((char*)d_ws + (1u << 19));    // (VOCAB+1)*512*4 = 62 KB

  hipMemsetAsync(d_ws, 0, 8192, stream);
  build_G<<<VOCAB + 1, 512, 0, stream>>>(emb, W_ih, b_ih, b_hh, G_tab);
  decoder_kernel<<<2 * BATCH, NTH, 0, stream>>>(key, value, y, emb, W_ih, W_hh,
                                                b_cp, G_tab, out, msgs, flags);
}